// Round 5
// baseline (324.315 us; speedup 1.0000x reference)
//
#include <hip/hip_runtime.h>
#include <hip/hip_bf16.h>
#include <cstdint>
#include <cstddef>

#define KDIM 4096   // IN_F
#define NDIM 4096   // OUT_F

typedef __attribute__((ext_vector_type(8))) short short8;
typedef __attribute__((ext_vector_type(8))) __bf16 bf16x8;
typedef __attribute__((ext_vector_type(4))) float f32x4;
typedef __attribute__((ext_vector_type(16))) float f32x16;

// f32 -> bf16, round-to-nearest-even
__device__ __forceinline__ unsigned short bf16_rne(float f) {
    unsigned int u = __builtin_bit_cast(unsigned int, f);
    u += 0x7fffu + ((u >> 16) & 1u);
    return (unsigned short)(u >> 16);
}

__device__ __forceinline__ void gload_lds16(const unsigned short* g, unsigned short* l) {
    __builtin_amdgcn_global_load_lds(
        (const __attribute__((address_space(1))) unsigned int*)g,
        (__attribute__((address_space(3))) unsigned int*)l,
        16, 0, 0);
}

// ---------------- preprocess: x fp32 -> bf16 ----------------
__global__ void cvt_x_kernel(const float* __restrict__ x, unsigned short* __restrict__ xb) {
    long i = (long)blockIdx.x * blockDim.x + threadIdx.x;   // one thread = 8 elems
    float4 a = ((const float4*)x)[2 * i];
    float4 b = ((const float4*)x)[2 * i + 1];
    union { unsigned short u[8]; short8 v; } r;
    r.u[0] = bf16_rne(a.x); r.u[1] = bf16_rne(a.y);
    r.u[2] = bf16_rne(a.z); r.u[3] = bf16_rne(a.w);
    r.u[4] = bf16_rne(b.x); r.u[5] = bf16_rne(b.y);
    r.u[6] = bf16_rne(b.z); r.u[7] = bf16_rne(b.w);
    ((short8*)xb)[i] = r.v;
}

// ---------------- preprocess: dequant 2-bit W -> bf16 [N][K] ----------------
__global__ void dequant_w_kernel(const int* __restrict__ wp,
                                 const float* __restrict__ scales,
                                 const float* __restrict__ zeros,
                                 unsigned short* __restrict__ wb) {
    long i = (long)blockIdx.x * blockDim.x + threadIdx.x;   // one thread = 2 packed ints = 8 weights
    int2 p = ((const int2*)wp)[i];
    long base = i * 8;                    // flat weight index (o*4096 + k)
    int o = (int)(base >> 12);
    int g = (int)((base & 4095) >> 7);    // all 8 weights in same group (8 | 128)
    float s = scales[o * 32 + g];
    float z = zeros[o * 32 + g];
    union { unsigned short u[8]; short8 v; } r;
#pragma unroll
    for (int j = 0; j < 4; ++j) {
        r.u[j]     = bf16_rne((float)((p.x >> (2 * j)) & 3) * s + z);
        r.u[4 + j] = bf16_rne((float)((p.y >> (2 * j)) & 3) * s + z);
    }
    ((short8*)wb)[i] = r.v;
}

// ---------------- 256x256 free-run GEMM, 32x32x16 MFMA ----------------
// C[M][N] = A[M][K](bf16) * B[N][K](bf16)^T + bias.
// R5 redesign: R4's 8-barrier/K-tile phase structure serialized the LDS-read
// window against the MFMA window (model: 2306cy reads + 2483cy MFMA = 4992cy
// observed). AITER-style minimal sync: 2 barriers + 1 counted vmcnt per
// K-tile, ~32 MFMA between barriers; per-wave program order + wave drift
// overlaps LDS and MFMA pipes. 32x32x16 MFMA raises FLOP/cy 2075->2495 TF.
//
// SYNC LEDGER (buf d = tile t, NT=64):
//  iter t: [24 ds_read -> 32 MFMA]  (reads provably returned before last MFMA
//          via data dep; sched fence stops sinking past barrier)
//  B1     : all waves' reads of tile t done -> buf d is free
//  stage  : 8 gload_lds of tile t+2 -> buf d  (disjoint from d^1 being read next)
//  vmcnt(8): outstanding = t+1's 8 + t+2's 8 = 16 -> drains t+1 fully
//  B2     : every wave passed vmcnt(8) -> tile t+1 resident cross-wave
//  tail   : t2 clamped (idempotent/dead rewrites keep count uniform);
//           post-loop vmcnt(0) so no LDS-DMA outlives the loop.
// Swizzle (both-sides, proven R4): LDS(r,8j) = G(r, 8*(j ^ (r&7))); read at
// elem 8*((2s+h)^(r&7)), h=lane>>5, slice s=0..3; r&7 == lane&7.

#define WGBAR \
    __builtin_amdgcn_sched_barrier(0); \
    __builtin_amdgcn_s_barrier(); \
    __builtin_amdgcn_sched_barrier(0);

__global__ __launch_bounds__(512, 2) void gemm256(const unsigned short* __restrict__ A,
                                                  const unsigned short* __restrict__ B,
                                                  const float* __restrict__ bias,
                                                  float* __restrict__ C) {
    __shared__ __align__(16) unsigned short sm[65536];   // 128 KiB: buf d: A@d*32768, B@d*32768+16384

    const int tid = threadIdx.x;
    const int w64 = tid >> 6;
    const int lane = tid & 63;

    // T1: bijective XCD swizzle (gridDim.x % 8 == 0)
    const int nwg = gridDim.x;
    const int chunk = nwg >> 3;
    const int s_id = (blockIdx.x & 7) * chunk + (blockIdx.x >> 3);
    const int nm = nwg >> 4;              // M tiles (N tiles fixed at 16)
    const int bm = s_id % nm;
    const int bn = s_id / nm;
    const int row0 = bm * 256;
    const int col0 = bn * 256;

    const int wr = w64 >> 2;              // 0..1 (M half: 128 rows)
    const int wc = w64 & 3;               // 0..3 (N quarter: 64 cols)

    // ---- stage addressing (identical to R4, proven): row srow(+64,+128h), swizzled k
    const int srow = tid >> 3;                                  // 0..63
    const int swzk = 8 * ((tid & 7) ^ ((tid >> 3) & 7));        // pre-swizzled src elem
    const unsigned short* srcA = A + (size_t)(row0 + srow) * KDIM + swzk;
    const unsigned short* srcB = B + (size_t)(col0 + srow) * KDIM + swzk;

    // ---- frag addressing: 32x32x16 A/B layout: row|col = lane&31, k = (lane>>5)*8 (+slice*16)
    const int lr5 = lane & 31;
    const int h = lane >> 5;
    const int l7 = lane & 7;
    int sw[4];
#pragma unroll
    for (int s = 0; s < 4; ++s) sw[s] = 8 * ((2 * s + h) ^ l7);
    const int aBase = (wr * 128 + lr5) * 64;            // + mt*32*64
    const int bBase = 16384 + (wc * 64 + lr5) * 64;     // + nt*32*64

    f32x16 acc[4][2] = {};
    short8 aF[4][2], bF[2][2];

    auto stageA = [&](int hh, int tile, int db) {
        const unsigned short* g = srcA + (size_t)hh * 128 * KDIM + (size_t)tile * 64;
        unsigned short* l = &sm[db * 32768 + hh * 8192 + w64 * 512];
        gload_lds16(g, l);
        gload_lds16(g + (size_t)64 * KDIM, l + 4096);
    };
    auto stageB = [&](int hh, int tile, int db) {
        const unsigned short* g = srcB + (size_t)hh * 128 * KDIM + (size_t)tile * 64;
        unsigned short* l = &sm[db * 32768 + 16384 + hh * 8192 + w64 * 512];
        gload_lds16(g, l);
        gload_lds16(g + (size_t)64 * KDIM, l + 4096);
    };

    const int NT = KDIM / 64;   // 64 K-tiles

    // ---- prologue: tile0 -> buf0, tile1 -> buf1 (8 loads each)
    stageA(0, 0, 0); stageA(1, 0, 0); stageB(0, 0, 0); stageB(1, 0, 0);
    stageA(0, 1, 1); stageA(1, 1, 1); stageB(0, 1, 1); stageB(1, 1, 1);
    __builtin_amdgcn_sched_barrier(0);
    asm volatile("s_waitcnt vmcnt(8)" ::: "memory");   // tile0 resident (tile1 in flight)
    WGBAR

    for (int t = 0; t < NT; ++t) {
        const int d = t & 1;
        const int dOff = d * 32768;
        const int t2 = (t + 2 < NT) ? t + 2 : NT - 1;   // clamped tail: dead/idempotent writes

        // ---- compute tile t: two k-halves (slices {0,1} then {2,3}) ----
#pragma unroll
        for (int p = 0; p < 2; ++p) {
#pragma unroll
            for (int mt = 0; mt < 4; ++mt) {
                aF[mt][0] = *(const short8*)&sm[dOff + aBase + mt * 2048 + sw[2 * p]];
                aF[mt][1] = *(const short8*)&sm[dOff + aBase + mt * 2048 + sw[2 * p + 1]];
            }
#pragma unroll
            for (int nt = 0; nt < 2; ++nt) {
                bF[nt][0] = *(const short8*)&sm[dOff + bBase + nt * 2048 + sw[2 * p]];
                bF[nt][1] = *(const short8*)&sm[dOff + bBase + nt * 2048 + sw[2 * p + 1]];
            }
            __builtin_amdgcn_s_setprio(1);
#pragma unroll
            for (int s = 0; s < 2; ++s)
#pragma unroll
                for (int mt = 0; mt < 4; ++mt)
#pragma unroll
                    for (int nt = 0; nt < 2; ++nt)
                        acc[mt][nt] = __builtin_amdgcn_mfma_f32_32x32x16_bf16(
                            __builtin_bit_cast(bf16x8, aF[mt][s]),
                            __builtin_bit_cast(bf16x8, bF[nt][s]),
                            acc[mt][nt], 0, 0, 0);
            __builtin_amdgcn_s_setprio(0);
        }

        // ---- B1: all reads of tile t done -> buf d free for staging ----
        WGBAR
        stageB(0, t2, d); stageB(1, t2, d);
        stageA(0, t2, d); stageA(1, t2, d);
        __builtin_amdgcn_sched_barrier(0);
        asm volatile("s_waitcnt vmcnt(8)" ::: "memory");   // drain tile t+1's loads
        __builtin_amdgcn_sched_barrier(0);
        // ---- B2: tile t+1 resident cross-wave ----
        WGBAR
    }

    // no LDS-DMA may outlive the loop
    __builtin_amdgcn_sched_barrier(0);
    asm volatile("s_waitcnt vmcnt(0)" ::: "memory");
    __builtin_amdgcn_sched_barrier(0);

    // ---- epilogue: 32x32 C/D layout: col=lane&31, row=(reg&3)+8*(reg>>2)+4*(lane>>5)
#pragma unroll
    for (int mt = 0; mt < 4; ++mt) {
#pragma unroll
        for (int nt = 0; nt < 2; ++nt) {
            int col = col0 + wc * 64 + nt * 32 + lr5;
            float bz = bias[col];
#pragma unroll
            for (int r = 0; r < 16; ++r) {
                int row = row0 + wr * 128 + mt * 32 + (r & 3) + 8 * (r >> 2) + 4 * h;
                C[(size_t)row * NDIM + col] = acc[mt][nt][r] + bz;
            }
        }
    }
}

// ---------------- emergency fallback (ws too small / odd shape): exact fp32 ----------------
__global__ void fallback_kernel(const float* __restrict__ x, const int* __restrict__ wp,
                                const float* __restrict__ scales, const float* __restrict__ zeros,
                                const float* __restrict__ bias, float* __restrict__ out) {
    int o = blockIdx.x * 256 + threadIdx.x;
    int m = blockIdx.y;
    __shared__ float xs[KDIM];
    for (int i = threadIdx.x; i < KDIM; i += 256) xs[i] = x[(size_t)m * KDIM + i];
    __syncthreads();
    float acc = 0.f;
    for (int g = 0; g < 32; ++g) {
        float s = scales[o * 32 + g], z = zeros[o * 32 + g];
        float aq = 0.f, ax = 0.f;
        for (int j = 0; j < 32; ++j) {
            int p = wp[o * 1024 + g * 32 + j];
            int kb = g * 128 + j * 4;
#pragma unroll
            for (int q = 0; q < 4; ++q) {
                float xv = xs[kb + q];
                aq += xv * (float)((p >> (2 * q)) & 3);
                ax += xv;
            }
        }
        acc += s * aq + z * ax;
    }
    out[(size_t)m * NDIM + o] = acc + bias[o];
}

extern "C" void kernel_launch(void* const* d_in, const int* in_sizes, int n_in,
                              void* d_out, int out_size, void* d_ws, size_t ws_size,
                              hipStream_t stream) {
    const float* x      = (const float*)d_in[0];
    const int*   wp     = (const int*)d_in[1];
    const float* scales = (const float*)d_in[2];
    const float* zeros  = (const float*)d_in[3];
    const float* bias   = (const float*)d_in[4];
    float* out = (float*)d_out;

    const long M = (long)in_sizes[0] / KDIM;            // 8192
    const long PACKED = (long)in_sizes[1];              // 4194304
    const size_t need = (size_t)M * KDIM * 2 + (size_t)NDIM * KDIM * 2;  // 96 MB

    if (ws_size >= need && (M % 256) == 0) {
        unsigned short* xb = (unsigned short*)d_ws;
        unsigned short* wb = xb + (size_t)M * KDIM;
        cvt_x_kernel<<<(M * KDIM / 8) / 256, 256, 0, stream>>>(x, xb);
        dequant_w_kernel<<<(PACKED / 2) / 256, 256, 0, stream>>>(wp, scales, zeros, wb);
        int nwg = (int)(M / 256) * (NDIM / 256);        // 32*16 = 512, %8==0
        gemm256<<<nwg, 512, 0, stream>>>(xb, wb, bias, out);
    } else {
        dim3 grid(NDIM / 256, M);
        fallback_kernel<<<grid, 256, 0, stream>>>(x, wp, scales, zeros, bias, out);
    }
}

// Round 6
// 303.114 us; speedup vs baseline: 1.0699x; 1.0699x over previous
//
#include <hip/hip_runtime.h>
#include <hip/hip_bf16.h>
#include <cstdint>
#include <cstddef>

#define KDIM 4096   // IN_F
#define NDIM 4096   // OUT_F

typedef __attribute__((ext_vector_type(8))) short short8;
typedef __attribute__((ext_vector_type(8))) __bf16 bf16x8;
typedef __attribute__((ext_vector_type(4))) float f32x4;

// f32 -> bf16, round-to-nearest-even
__device__ __forceinline__ unsigned short bf16_rne(float f) {
    unsigned int u = __builtin_bit_cast(unsigned int, f);
    u += 0x7fffu + ((u >> 16) & 1u);
    return (unsigned short)(u >> 16);
}

__device__ __forceinline__ void gload_lds16(const unsigned short* g, unsigned short* l) {
    __builtin_amdgcn_global_load_lds(
        (const __attribute__((address_space(1))) unsigned int*)g,
        (__attribute__((address_space(3))) unsigned int*)l,
        16, 0, 0);
}

// ---------------- preprocess: x fp32 -> bf16 ----------------
__global__ void cvt_x_kernel(const float* __restrict__ x, unsigned short* __restrict__ xb) {
    long i = (long)blockIdx.x * blockDim.x + threadIdx.x;   // one thread = 8 elems
    float4 a = ((const float4*)x)[2 * i];
    float4 b = ((const float4*)x)[2 * i + 1];
    union { unsigned short u[8]; short8 v; } r;
    r.u[0] = bf16_rne(a.x); r.u[1] = bf16_rne(a.y);
    r.u[2] = bf16_rne(a.z); r.u[3] = bf16_rne(a.w);
    r.u[4] = bf16_rne(b.x); r.u[5] = bf16_rne(b.y);
    r.u[6] = bf16_rne(b.z); r.u[7] = bf16_rne(b.w);
    ((short8*)xb)[i] = r.v;
}

// ---------------- preprocess: dequant 2-bit W -> bf16 [N][K] ----------------
__global__ void dequant_w_kernel(const int* __restrict__ wp,
                                 const float* __restrict__ scales,
                                 const float* __restrict__ zeros,
                                 unsigned short* __restrict__ wb) {
    long i = (long)blockIdx.x * blockDim.x + threadIdx.x;   // one thread = 2 packed ints = 8 weights
    int2 p = ((const int2*)wp)[i];
    long base = i * 8;                    // flat weight index (o*4096 + k)
    int o = (int)(base >> 12);
    int g = (int)((base & 4095) >> 7);    // all 8 weights in same group (8 | 128)
    float s = scales[o * 32 + g];
    float z = zeros[o * 32 + g];
    union { unsigned short u[8]; short8 v; } r;
#pragma unroll
    for (int j = 0; j < 4; ++j) {
        r.u[j]     = bf16_rne((float)((p.x >> (2 * j)) & 3) * s + z);
        r.u[4 + j] = bf16_rne((float)((p.y >> (2 * j)) & 3) * s + z);
    }
    ((short8*)wb)[i] = r.v;
}

// ---------------- 256x256 free-run GEMM, 16x16x32 MFMA ----------------
// C[M][N] = A[M][K](bf16) * B[N][K](bf16)^T + bias.
// R6: R4's PROVEN 16x16 fragment/swizzle byte math (0 bank conflicts) +
// R5's PROVEN 2-barrier/tile free-run ledger. No intra-tile barriers: the
// compiler's fine-grained lgkmcnt lets next-quad ds_reads drain under the
// current quad's MFMAs (the LDS-read window ~2300cy vs MFMA ~620cy was
// serialized by R4's phase barriers — that serialization is the target).
// aG[] = separate regs for A m-half1 so no WAR blocks read hoisting.
//
// SYNC LEDGER (buf d = tile t, NT=64):
//  compute: 24 ds_read -> 64 MFMA; every read feeds an MFMA before B1 (data
//           dep) => all reads of buf d returned before B1.
//  B1     : cross-wave: buf d free.
//  stage  : 8 gload_lds tile t+2 -> buf d (disjoint from buf d^1 read next).
//  vmcnt(8): outstanding = t+1's 8 + t+2's 8 => drains t+1 fully.
//  B2     : tile t+1 resident cross-wave. sched_barrier fences stop reads
//           hoisting above B2 / stages sinking below.
//  tail   : t2 clamped => dead/idempotent rewrites; post-loop vmcnt(0).
// Swizzle (both sides, proven R4): LDS(r,8j)=G(r,8*(j^(r&7))); read elem
// 8*((4s+lk4)^(r&7)), r&7 == lane&7.

#define WGBAR \
    __builtin_amdgcn_sched_barrier(0); \
    __builtin_amdgcn_s_barrier(); \
    __builtin_amdgcn_sched_barrier(0);

#define QUAD(af, mh, nh) \
    _Pragma("unroll") \
    for (int s_ = 0; s_ < 2; ++s_) { \
      _Pragma("unroll") \
      for (int mi_ = 0; mi_ < 4; ++mi_) { \
        _Pragma("unroll") \
        for (int ni_ = 0; ni_ < 2; ++ni_) { \
          acc[(mh)*4+mi_][(nh)*2+ni_] = __builtin_amdgcn_mfma_f32_16x16x32_bf16( \
            __builtin_bit_cast(bf16x8, af[mi_][s_]), \
            __builtin_bit_cast(bf16x8, bF[(nh)*2+ni_][s_]), \
            acc[(mh)*4+mi_][(nh)*2+ni_], 0, 0, 0); \
        } } }

__global__ __launch_bounds__(512, 2) void gemm256(const unsigned short* __restrict__ A,
                                                  const unsigned short* __restrict__ B,
                                                  const float* __restrict__ bias,
                                                  float* __restrict__ C) {
    __shared__ __align__(16) unsigned short sm[65536];   // 128 KiB: buf d: A@d*32768, B@d*32768+16384

    const int tid = threadIdx.x;
    const int w64 = tid >> 6;
    const int lane = tid & 63;

    // T1: bijective XCD swizzle (gridDim.x % 8 == 0)
    const int nwg = gridDim.x;
    const int chunk = nwg >> 3;
    const int s_id = (blockIdx.x & 7) * chunk + (blockIdx.x >> 3);
    const int nm = nwg >> 4;              // M tiles (N tiles fixed at 16)
    const int bm = s_id % nm;
    const int bn = s_id / nm;
    const int row0 = bm * 256;
    const int col0 = bn * 256;

    const int wr = w64 >> 2;              // 0..1 (M half: 128 rows)
    const int wc = w64 & 3;               // 0..3 (N quarter: 64 cols)

    // ---- stage addressing (proven R4): row srow(+64,+128h), swizzled k
    const int srow = tid >> 3;                                  // 0..63
    const int swzk = 8 * ((tid & 7) ^ ((tid >> 3) & 7));        // pre-swizzled src elem
    const unsigned short* srcA = A + (size_t)(row0 + srow) * KDIM + swzk;
    const unsigned short* srcB = B + (size_t)(col0 + srow) * KDIM + swzk;

    // ---- frag addressing (proven R4, 0 conflicts): elem = R*64 + 8*((4s+lk4)^(R&7))
    const int lr = lane & 15;
    const int lk4 = lane >> 4;
    const int l7 = lane & 7;
    const int sw0 = 8 * (((0 << 2) + lk4) ^ l7);
    const int sw1 = 8 * (((1 << 2) + lk4) ^ l7);
    const int aBase = (wr * 128 + lr) * 64;
    const int bBase = 16384 + (wc * 64 + lr) * 64;

    f32x4 acc[8][4] = {};
    short8 aF[4][2], aG[4][2], bF[4][2];

    auto stageA = [&](int hh, int tile, int db) {
        const unsigned short* g = srcA + (size_t)hh * 128 * KDIM + (size_t)tile * 64;
        unsigned short* l = &sm[db * 32768 + hh * 8192 + w64 * 512];
        gload_lds16(g, l);
        gload_lds16(g + (size_t)64 * KDIM, l + 4096);
    };
    auto stageB = [&](int hh, int tile, int db) {
        const unsigned short* g = srcB + (size_t)hh * 128 * KDIM + (size_t)tile * 64;
        unsigned short* l = &sm[db * 32768 + 16384 + hh * 8192 + w64 * 512];
        gload_lds16(g, l);
        gload_lds16(g + (size_t)64 * KDIM, l + 4096);
    };

    const int NT = KDIM / 64;   // 64 K-tiles

    // ---- prologue: tile0 -> buf0, tile1 -> buf1 (8 loads each)
    stageA(0, 0, 0); stageA(1, 0, 0); stageB(0, 0, 0); stageB(1, 0, 0);
    stageA(0, 1, 1); stageA(1, 1, 1); stageB(0, 1, 1); stageB(1, 1, 1);
    __builtin_amdgcn_sched_barrier(0);
    asm volatile("s_waitcnt vmcnt(8)" ::: "memory");   // tile0 resident (tile1 in flight)
    WGBAR

    for (int t = 0; t < NT; ++t) {
        const int d = t & 1;
        const int dOff = d * 32768;
        const int t2 = (t + 2 < NT) ? t + 2 : NT - 1;   // clamped tail: dead/idempotent writes

        // ---- free-run compute of tile t (no intra-tile barriers/fences) ----
        // Q1 reads: A m-half0 (8) + B n-half0 (4)
#pragma unroll
        for (int mi = 0; mi < 4; ++mi) {
            aF[mi][0] = *(const short8*)&sm[dOff + aBase + mi * 1024 + sw0];
            aF[mi][1] = *(const short8*)&sm[dOff + aBase + mi * 1024 + sw1];
        }
#pragma unroll
        for (int ni = 0; ni < 2; ++ni) {
            bF[ni][0] = *(const short8*)&sm[dOff + bBase + ni * 1024 + sw0];
            bF[ni][1] = *(const short8*)&sm[dOff + bBase + ni * 1024 + sw1];
        }
        // Q2+Q3 reads issued early (compiler may drain them under Q1/Q2 MFMAs)
#pragma unroll
        for (int ni = 2; ni < 4; ++ni) {
            bF[ni][0] = *(const short8*)&sm[dOff + bBase + ni * 1024 + sw0];
            bF[ni][1] = *(const short8*)&sm[dOff + bBase + ni * 1024 + sw1];
        }
#pragma unroll
        for (int mi = 0; mi < 4; ++mi) {
            aG[mi][0] = *(const short8*)&sm[dOff + aBase + (4 + mi) * 1024 + sw0];
            aG[mi][1] = *(const short8*)&sm[dOff + aBase + (4 + mi) * 1024 + sw1];
        }

        __builtin_amdgcn_s_setprio(1);
        QUAD(aF, 0, 0)
        QUAD(aF, 0, 1)
        QUAD(aG, 1, 0)
        QUAD(aG, 1, 1)
        __builtin_amdgcn_s_setprio(0);

        // ---- B1: all reads of tile t done (data-dep) -> buf d free ----
        WGBAR
        stageB(0, t2, d); stageB(1, t2, d);
        stageA(0, t2, d); stageA(1, t2, d);
        __builtin_amdgcn_sched_barrier(0);
        asm volatile("s_waitcnt vmcnt(8)" ::: "memory");   // drain tile t+1's loads
        __builtin_amdgcn_sched_barrier(0);
        // ---- B2: tile t+1 resident cross-wave ----
        WGBAR
    }

    // no LDS-DMA may outlive the loop
    __builtin_amdgcn_sched_barrier(0);
    asm volatile("s_waitcnt vmcnt(0)" ::: "memory");
    __builtin_amdgcn_sched_barrier(0);

    // ---- epilogue: C/D layout col=lane&15, row=(lane>>4)*4+r
#pragma unroll
    for (int m = 0; m < 8; ++m) {
#pragma unroll
        for (int n = 0; n < 4; ++n) {
            int col = col0 + wc * 64 + n * 16 + lr;
            float bz = bias[col];
#pragma unroll
            for (int r = 0; r < 4; ++r) {
                int row = row0 + wr * 128 + m * 16 + lk4 * 4 + r;
                C[(size_t)row * NDIM + col] = acc[m][n][r] + bz;
            }
        }
    }
}

// ---------------- emergency fallback (ws too small / odd shape): exact fp32 ----------------
__global__ void fallback_kernel(const float* __restrict__ x, const int* __restrict__ wp,
                                const float* __restrict__ scales, const float* __restrict__ zeros,
                                const float* __restrict__ bias, float* __restrict__ out) {
    int o = blockIdx.x * 256 + threadIdx.x;
    int m = blockIdx.y;
    __shared__ float xs[KDIM];
    for (int i = threadIdx.x; i < KDIM; i += 256) xs[i] = x[(size_t)m * KDIM + i];
    __syncthreads();
    float acc = 0.f;
    for (int g = 0; g < 32; ++g) {
        float s = scales[o * 32 + g], z = zeros[o * 32 + g];
        float aq = 0.f, ax = 0.f;
        for (int j = 0; j < 32; ++j) {
            int p = wp[o * 1024 + g * 32 + j];
            int kb = g * 128 + j * 4;
#pragma unroll
            for (int q = 0; q < 4; ++q) {
                float xv = xs[kb + q];
                aq += xv * (float)((p >> (2 * q)) & 3);
                ax += xv;
            }
        }
        acc += s * aq + z * ax;
    }
    out[(size_t)m * NDIM + o] = acc + bias[o];
}

extern "C" void kernel_launch(void* const* d_in, const int* in_sizes, int n_in,
                              void* d_out, int out_size, void* d_ws, size_t ws_size,
                              hipStream_t stream) {
    const float* x      = (const float*)d_in[0];
    const int*   wp     = (const int*)d_in[1];
    const float* scales = (const float*)d_in[2];
    const float* zeros  = (const float*)d_in[3];
    const float* bias   = (const float*)d_in[4];
    float* out = (float*)d_out;

    const long M = (long)in_sizes[0] / KDIM;            // 8192
    const long PACKED = (long)in_sizes[1];              // 4194304
    const size_t need = (size_t)M * KDIM * 2 + (size_t)NDIM * KDIM * 2;  // 96 MB

    if (ws_size >= need && (M % 256) == 0) {
        unsigned short* xb = (unsigned short*)d_ws;
        unsigned short* wb = xb + (size_t)M * KDIM;
        cvt_x_kernel<<<(M * KDIM / 8) / 256, 256, 0, stream>>>(x, xb);
        dequant_w_kernel<<<(PACKED / 2) / 256, 256, 0, stream>>>(wp, scales, zeros, wb);
        int nwg = (int)(M / 256) * (NDIM / 256);        // 32*16 = 512, %8==0
        gemm256<<<nwg, 512, 0, stream>>>(xb, wb, bias, out);
    } else {
        dim3 grid(NDIM / 256, M);
        fallback_kernel<<<grid, 256, 0, stream>>>(x, wp, scales, zeros, bias, out);
    }
}

// Round 7
// 286.146 us; speedup vs baseline: 1.1334x; 1.0593x over previous
//
#include <hip/hip_runtime.h>
#include <hip/hip_bf16.h>
#include <cstdint>
#include <cstddef>

#define KDIM 4096   // IN_F
#define NDIM 4096   // OUT_F

typedef __attribute__((ext_vector_type(8))) short short8;
typedef __attribute__((ext_vector_type(8))) __bf16 bf16x8;
typedef __attribute__((ext_vector_type(4))) float f32x4;

// f32 -> bf16, round-to-nearest-even
__device__ __forceinline__ unsigned short bf16_rne(float f) {
    unsigned int u = __builtin_bit_cast(unsigned int, f);
    u += 0x7fffu + ((u >> 16) & 1u);
    return (unsigned short)(u >> 16);
}

__device__ __forceinline__ void gload_lds16(const unsigned short* g, unsigned short* l) {
    __builtin_amdgcn_global_load_lds(
        (const __attribute__((address_space(1))) unsigned int*)g,
        (__attribute__((address_space(3))) unsigned int*)l,
        16, 0, 0);
}

// ---------------- preprocess: x fp32 -> bf16 ----------------
__global__ void cvt_x_kernel(const float* __restrict__ x, unsigned short* __restrict__ xb) {
    long i = (long)blockIdx.x * blockDim.x + threadIdx.x;   // one thread = 8 elems
    float4 a = ((const float4*)x)[2 * i];
    float4 b = ((const float4*)x)[2 * i + 1];
    union { unsigned short u[8]; short8 v; } r;
    r.u[0] = bf16_rne(a.x); r.u[1] = bf16_rne(a.y);
    r.u[2] = bf16_rne(a.z); r.u[3] = bf16_rne(a.w);
    r.u[4] = bf16_rne(b.x); r.u[5] = bf16_rne(b.y);
    r.u[6] = bf16_rne(b.z); r.u[7] = bf16_rne(b.w);
    ((short8*)xb)[i] = r.v;
}

// ---------------- preprocess: dequant 2-bit W -> bf16 [N][K] ----------------
__global__ void dequant_w_kernel(const int* __restrict__ wp,
                                 const float* __restrict__ scales,
                                 const float* __restrict__ zeros,
                                 unsigned short* __restrict__ wb) {
    long i = (long)blockIdx.x * blockDim.x + threadIdx.x;   // one thread = 2 packed ints = 8 weights
    int2 p = ((const int2*)wp)[i];
    long base = i * 8;                    // flat weight index (o*4096 + k)
    int o = (int)(base >> 12);
    int g = (int)((base & 4095) >> 7);    // all 8 weights in same group (8 | 128)
    float s = scales[o * 32 + g];
    float z = zeros[o * 32 + g];
    union { unsigned short u[8]; short8 v; } r;
#pragma unroll
    for (int j = 0; j < 4; ++j) {
        r.u[j]     = bf16_rne((float)((p.x >> (2 * j)) & 3) * s + z);
        r.u[4 + j] = bf16_rne((float)((p.y >> (2 * j)) & 3) * s + z);
    }
    ((short8*)wb)[i] = r.v;
}

// ---------------- 256x256 m201-style 8-phase GEMM ----------------
// C[M][N] = A[M][K](bf16) * B[N][K](bf16)^T + bias.
// 512 thr = 8 waves (2Mx4N), per-wave 128x64, BK=64, 2 K-tiles/iter,
// LDS 128 KiB (buf0 @0, buf1 @32768 shorts; each: A 16K shorts + B 16K).
// Per phase: {ds_reads | 1 half-tile stage (2 gloads) | [vmcnt(4) @P4,P8]
//   | s_barrier | lgkmcnt(0)+sched_barrier | setprio1 | 16 MFMA | setprio0
//   | s_barrier}.  NO other sched_barriers (m141 anti-pattern).
//
// REGION LEDGER (iter i: tile e=2i in buf0, o=2i+1 in buf1):
//  reads: buf0 A @P1,P3; buf0 B @P1,P2; buf1 A @P5,P7; buf1 B @P5,P6.
//  frees (cross-wave, own lgkmcnt(0) before own MFMA before end-barrier):
//   buf0.B after P2-end, buf0.A after P3-end, buf1.B after P6-end, buf1.A after P7-end.
//  stage ring: P1:A0(o)->buf1  P2:A1(o)->buf1   [buf1.A free since (i-1).P7]
//              P3:B0(e+2)->buf0 P4:B1(e+2)->buf0 [buf0.B free after P2]
//              P5:A0(e+2)->buf0 P6:A1(e+2)->buf0 [buf0.A free after P3]
//              P7:B0(o+2)->buf1 P8:B1(o+2)->buf1 [buf1.B free after P6]
//  vmcnt(4)@P4 (after P4 stage): leaves only P3,P4 in flight => buf1 of tile o
//   (B from (i-1).P7,P8 + A from P1,P2) resident before P5 reads. barrier => cross-wave.
//  vmcnt(4)@P8: leaves only P7,P8 => buf0 of tile e+2 (P3..P6) resident before (i+1).P1.
//  prologue: B(0),A(0)->buf0, B(1)->buf1 (12 loads), vmcnt(4) (buf0 resident,
//   buf1.B may fly - drained by iter0 P4), barrier.
//  tail: e2/o2 clamped => writes into already-dead regions; post-loop vmcnt(0).
// Swizzle (proven R4/R6, 0 conflicts): LDS(r,8j)=G(r,8*(j^(r&7))); read elem
//  R*64 + 8*((4s+lk4)^(R&7)), R&7 == lane&7.

#define PH_SYNC_MFMA \
    __builtin_amdgcn_s_barrier(); \
    asm volatile("s_waitcnt lgkmcnt(0)" ::: "memory"); \
    __builtin_amdgcn_sched_barrier(0); \
    __builtin_amdgcn_s_setprio(1);

#define PH_END \
    __builtin_amdgcn_s_setprio(0); \
    __builtin_amdgcn_s_barrier();

#define VMCNT4 \
    __builtin_amdgcn_sched_barrier(0); \
    asm volatile("s_waitcnt vmcnt(4)" ::: "memory"); \
    __builtin_amdgcn_sched_barrier(0);

#define RD_A(arr, DOFF, mh) \
    _Pragma("unroll") \
    for (int mi_ = 0; mi_ < 4; ++mi_) { \
        arr[mi_][0] = *(const short8*)&sm[(DOFF) + aBase + ((mh)*4 + mi_) * 1024 + sw0]; \
        arr[mi_][1] = *(const short8*)&sm[(DOFF) + aBase + ((mh)*4 + mi_) * 1024 + sw1]; \
    }

#define RD_B(DOFF, n0) \
    _Pragma("unroll") \
    for (int ni_ = 0; ni_ < 2; ++ni_) { \
        bF[(n0) + ni_][0] = *(const short8*)&sm[(DOFF) + bBase + ((n0) + ni_) * 1024 + sw0]; \
        bF[(n0) + ni_][1] = *(const short8*)&sm[(DOFF) + bBase + ((n0) + ni_) * 1024 + sw1]; \
    }

#define QUAD(af, mh, nh) \
    _Pragma("unroll") \
    for (int s_ = 0; s_ < 2; ++s_) { \
      _Pragma("unroll") \
      for (int mi_ = 0; mi_ < 4; ++mi_) { \
        _Pragma("unroll") \
        for (int ni_ = 0; ni_ < 2; ++ni_) { \
          acc[(mh)*4+mi_][(nh)*2+ni_] = __builtin_amdgcn_mfma_f32_16x16x32_bf16( \
            __builtin_bit_cast(bf16x8, af[mi_][s_]), \
            __builtin_bit_cast(bf16x8, bF[(nh)*2+ni_][s_]), \
            acc[(mh)*4+mi_][(nh)*2+ni_], 0, 0, 0); \
        } } }

__global__ __launch_bounds__(512, 2) void gemm256(const unsigned short* __restrict__ A,
                                                  const unsigned short* __restrict__ B,
                                                  const float* __restrict__ bias,
                                                  float* __restrict__ C) {
    __shared__ __align__(16) unsigned short sm[65536];   // 128 KiB

    const int tid = threadIdx.x;
    const int w64 = tid >> 6;
    const int lane = tid & 63;

    // T1: bijective XCD swizzle (gridDim.x % 8 == 0)
    const int nwg = gridDim.x;
    const int chunk = nwg >> 3;
    const int s_id = (blockIdx.x & 7) * chunk + (blockIdx.x >> 3);
    const int nm = nwg >> 4;              // M tiles (N tiles fixed at 16)
    const int bm = s_id % nm;
    const int bn = s_id / nm;
    const int row0 = bm * 256;
    const int col0 = bn * 256;

    const int wr = w64 >> 2;              // 0..1 (M half: 128 rows)
    const int wc = w64 & 3;               // 0..3 (N quarter: 64 cols)

    // ---- stage addressing (proven): row srow(+64,+128h), swizzled k
    const int srow = tid >> 3;                                  // 0..63
    const int swzk = 8 * ((tid & 7) ^ ((tid >> 3) & 7));        // pre-swizzled src elem
    const unsigned short* srcA = A + (size_t)(row0 + srow) * KDIM + swzk;
    const unsigned short* srcB = B + (size_t)(col0 + srow) * KDIM + swzk;

    // ---- frag addressing (proven, 0 conflicts)
    const int lr = lane & 15;
    const int lk4 = lane >> 4;
    const int l7 = lane & 7;
    const int sw0 = 8 * (((0 << 2) + lk4) ^ l7);
    const int sw1 = 8 * (((1 << 2) + lk4) ^ l7);
    const int aBase = (wr * 128 + lr) * 64;
    const int bBase = 16384 + (wc * 64 + lr) * 64;

    f32x4 acc[8][4] = {};
    short8 aF[4][2], aG[4][2], bF[4][2];

    auto stageA = [&](int hh, int tile, int db) {
        const unsigned short* g = srcA + (size_t)hh * 128 * KDIM + (size_t)tile * 64;
        unsigned short* l = &sm[db * 32768 + hh * 8192 + w64 * 512];
        gload_lds16(g, l);
        gload_lds16(g + (size_t)64 * KDIM, l + 4096);
    };
    auto stageB = [&](int hh, int tile, int db) {
        const unsigned short* g = srcB + (size_t)hh * 128 * KDIM + (size_t)tile * 64;
        unsigned short* l = &sm[db * 32768 + 16384 + hh * 8192 + w64 * 512];
        gload_lds16(g, l);
        gload_lds16(g + (size_t)64 * KDIM, l + 4096);
    };

    const int NT = KDIM / 64;   // 64 K-tiles (even)

    // ---- prologue: tile0 -> buf0 (4 halves), tile1 B -> buf1 (2 halves)
    stageB(0, 0, 0); stageB(1, 0, 0); stageA(0, 0, 0); stageA(1, 0, 0);
    stageB(0, 1, 1); stageB(1, 1, 1);
    VMCNT4                      // buf0 fully resident; buf1.B may fly
    __builtin_amdgcn_s_barrier();

    for (int i = 0; i < NT / 2; ++i) {
        const int e = 2 * i;
        const int o = e + 1;
        const int e2 = (e + 2 < NT) ? e + 2 : e;   // clamped tail: dead writes
        const int o2 = (o + 2 < NT) ? o + 2 : o;

        // ================= phases 1-4: tile e (buf0 @0) =================
        // P1: reads A-h0 + B n0-1, stage A0(o)->buf1
        RD_A(aF, 0, 0)
        RD_B(0, 0)
        stageA(0, o, 1);
        PH_SYNC_MFMA
        QUAD(aF, 0, 0)
        PH_END
        // P2: reads B n2-3, stage A1(o)->buf1
        RD_B(0, 2)
        stageA(1, o, 1);
        PH_SYNC_MFMA
        QUAD(aF, 0, 1)
        PH_END
        // P3: reads A-h1, stage B0(e+2)->buf0
        RD_A(aG, 0, 1)
        stageB(0, e2, 0);
        PH_SYNC_MFMA
        QUAD(aG, 1, 0)
        PH_END
        // P4: stage B1(e+2)->buf0, vmcnt(4) => tile o resident
        stageB(1, e2, 0);
        VMCNT4
        PH_SYNC_MFMA
        QUAD(aG, 1, 1)
        PH_END

        // ================= phases 5-8: tile o (buf1 @32768) =================
        // P5: reads A-h0 + B n0-1, stage A0(e+2)->buf0
        RD_A(aF, 32768, 0)
        RD_B(32768, 0)
        stageA(0, e2, 0);
        PH_SYNC_MFMA
        QUAD(aF, 0, 0)
        PH_END
        // P6: reads B n2-3, stage A1(e+2)->buf0
        RD_B(32768, 2)
        stageA(1, e2, 0);
        PH_SYNC_MFMA
        QUAD(aF, 0, 1)
        PH_END
        // P7: reads A-h1, stage B0(o+2)->buf1
        RD_A(aG, 32768, 1)
        stageB(0, o2, 1);
        PH_SYNC_MFMA
        QUAD(aG, 1, 0)
        PH_END
        // P8: stage B1(o+2)->buf1, vmcnt(4) => tile e+2 resident
        stageB(1, o2, 1);
        VMCNT4
        PH_SYNC_MFMA
        QUAD(aG, 1, 1)
        PH_END
    }

    // no LDS-DMA may outlive the loop
    __builtin_amdgcn_sched_barrier(0);
    asm volatile("s_waitcnt vmcnt(0)" ::: "memory");
    __builtin_amdgcn_sched_barrier(0);

    // ---- epilogue: C/D layout col=lane&15, row=(lane>>4)*4+r
#pragma unroll
    for (int m = 0; m < 8; ++m) {
#pragma unroll
        for (int n = 0; n < 4; ++n) {
            int col = col0 + wc * 64 + n * 16 + lr;
            float bz = bias[col];
#pragma unroll
            for (int r = 0; r < 4; ++r) {
                int row = row0 + wr * 128 + m * 16 + lk4 * 4 + r;
                C[(size_t)row * NDIM + col] = acc[m][n][r] + bz;
            }
        }
    }
}

// ---------------- emergency fallback (ws too small / odd shape): exact fp32 ----------------
__global__ void fallback_kernel(const float* __restrict__ x, const int* __restrict__ wp,
                                const float* __restrict__ scales, const float* __restrict__ zeros,
                                const float* __restrict__ bias, float* __restrict__ out) {
    int o = blockIdx.x * 256 + threadIdx.x;
    int m = blockIdx.y;
    __shared__ float xs[KDIM];
    for (int i = threadIdx.x; i < KDIM; i += 256) xs[i] = x[(size_t)m * KDIM + i];
    __syncthreads();
    float acc = 0.f;
    for (int g = 0; g < 32; ++g) {
        float s = scales[o * 32 + g], z = zeros[o * 32 + g];
        float aq = 0.f, ax = 0.f;
        for (int j = 0; j < 32; ++j) {
            int p = wp[o * 1024 + g * 32 + j];
            int kb = g * 128 + j * 4;
#pragma unroll
            for (int q = 0; q < 4; ++q) {
                float xv = xs[kb + q];
                aq += xv * (float)((p >> (2 * q)) & 3);
                ax += xv;
            }
        }
        acc += s * aq + z * ax;
    }
    out[(size_t)m * NDIM + o] = acc + bias[o];
}

extern "C" void kernel_launch(void* const* d_in, const int* in_sizes, int n_in,
                              void* d_out, int out_size, void* d_ws, size_t ws_size,
                              hipStream_t stream) {
    const float* x      = (const float*)d_in[0];
    const int*   wp     = (const int*)d_in[1];
    const float* scales = (const float*)d_in[2];
    const float* zeros  = (const float*)d_in[3];
    const float* bias   = (const float*)d_in[4];
    float* out = (float*)d_out;

    const long M = (long)in_sizes[0] / KDIM;            // 8192
    const long PACKED = (long)in_sizes[1];              // 4194304
    const size_t need = (size_t)M * KDIM * 2 + (size_t)NDIM * KDIM * 2;  // 96 MB

    if (ws_size >= need && (M % 256) == 0) {
        unsigned short* xb = (unsigned short*)d_ws;
        unsigned short* wb = xb + (size_t)M * KDIM;
        cvt_x_kernel<<<(M * KDIM / 8) / 256, 256, 0, stream>>>(x, xb);
        dequant_w_kernel<<<(PACKED / 2) / 256, 256, 0, stream>>>(wp, scales, zeros, wb);
        int nwg = (int)(M / 256) * (NDIM / 256);        // 32*16 = 512, %8==0
        gemm256<<<nwg, 512, 0, stream>>>(xb, wb, bias, out);
    } else {
        dim3 grid(NDIM / 256, M);
        fallback_kernel<<<grid, 256, 0, stream>>>(x, wp, scales, zeros, bias, out);
    }
}